// Round 1
// baseline (825.344 us; speedup 1.0000x reference)
//
#include <hip/hip_runtime.h>
#include <hip/hip_bf16.h>

typedef __attribute__((ext_vector_type(8))) short bf16x8;
typedef __attribute__((ext_vector_type(16))) float f32x16;

#define DEVFN __device__ __forceinline__

constexpr int NFEAT = 32, NLAYER = 8, HID = 256;
constexpr int HS  = 264;   // h/t LDS stride (bf16 elements), 16B-aligned
constexpr int MXS = 40;    // mx LDS stride
constexpr int XS  = 33;    // x LDS stride (floats)
constexpr int PS  = 132;   // params LDS stride (floats)
constexpr int WIN_E  = 2 * 256 * 16;    // 8192
constexpr int WH_E   = 16 * 256 * 16;   // 65536
constexpr int WOUT_E = 16 * 512 * 16;   // 131072
constexpr int LAYER_E = WIN_E + 4 * WH_E + WOUT_E;  // 401408 bf16 elems
constexpr size_t WT_BYTES = (size_t)LAYER_E * NLAYER * 2;  // 6422528
constexpr size_t WS_NEEDED = WT_BYTES + NLAYER * 512 * 4 + 4;

constexpr float MIN_BIN = 1e-4f, MIN_SLOPE = 1e-4f;
constexpr float SOFTPLUS_OFF = 0.5411666f;           // log(expm1(1 - MIN_SLOPE))
constexpr float WSCALE = 20.0f - 8.0f * MIN_BIN;     // (RMAX-RMIN) - K*MIN_BIN

DEVFN unsigned short bf16r(float f) {              // fp32 -> bf16, RNE
    unsigned u = __float_as_uint(f);
    u += 0x7fffu + ((u >> 16) & 1u);
    return (unsigned short)(u >> 16);
}
DEVFN float bflo(unsigned v) { return __uint_as_float(v << 16); }
DEVFN float bfhi(unsigned v) { return __uint_as_float(v & 0xffff0000u); }
DEVFN void zacc(f32x16& a) {
#pragma unroll
    for (int i = 0; i < 16; i++) a[i] = 0.0f;
}

// ---------------- prep kernel: bf16 transposed weight tiles in ws ----------------
// wt layout per matrix: [kstep][n][16kk] with element = W[k=kstep*16+kk][n]
__global__ __launch_bounds__(256) void prep_kernel(
    const float* __restrict__ Win, const float* __restrict__ W1a, const float* __restrict__ W1b,
    const float* __restrict__ W2a, const float* __restrict__ W2b, const float* __restrict__ Wout,
    const float* __restrict__ bout, const float* __restrict__ scS,
    short* __restrict__ wt, float* __restrict__ bo_t, float* __restrict__ sld)
{
    __shared__ float lb[16 * 800];
    const int b = blockIdx.x, t = threadIdx.x;
    if (b < 16) {                       // W_in: (L,32,256), k-dim = 32 -> 2 ksteps
        int l = b >> 1, ks = b & 1;
        const float* src = Win + l * 32 * 256 + ks * 16 * 256;
#pragma unroll
        for (int i = 0; i < 16; i++) { int idx = t + i * 256; lb[idx] = src[idx]; }
        __syncthreads();
        short* dst = wt + (size_t)l * LAYER_E + ks * 4096;
#pragma unroll
        for (int i = 0; i < 16; i++) {
            int o = t + i * 256; int n = o >> 4, kk = o & 15;
            dst[o] = (short)bf16r(lb[kk * 256 + n]);
        }
    } else if (b < 528) {               // W1a/W1b/W2a/W2b: 256x256, 16 ksteps each
        int id = b - 16; int l = id >> 6, mat = (id >> 4) & 3, ks = id & 15;
        const float* mats[4] = {W1a, W1b, W2a, W2b};
        const float* src = mats[mat] + l * 65536 + ks * 16 * 256;
#pragma unroll
        for (int i = 0; i < 16; i++) { int idx = t + i * 256; lb[idx] = src[idx]; }
        __syncthreads();
        short* dst = wt + (size_t)l * LAYER_E + WIN_E + mat * WH_E + ks * 4096;
#pragma unroll
        for (int i = 0; i < 16; i++) {
            int o = t + i * 256; int n = o >> 4, kk = o & 15;
            dst[o] = (short)bf16r(lb[kk * 256 + n]);
        }
    } else if (b < 656) {               // W_out: trim to unmasked cols, pad 25->32
        int id = b - 528; int l = id >> 4, ks = id & 15; int par = l & 1;
        const float* src = Wout + (size_t)l * 256 * 800 + ks * 16 * 800;
        for (int k = 0; k < 16; k++)
            for (int c = t; c < 800; c += 256) lb[k * 800 + c] = src[k * 800 + c];
        __syncthreads();
        short* dst = wt + (size_t)l * LAYER_E + WIN_E + 4 * WH_E + ks * 8192;
#pragma unroll
        for (int i = 0; i < 32; i++) {
            int o = t + i * 256; int c = o >> 4, kk = o & 15;
            int u = c >> 5, p = c & 31;
            float v = (p < 25) ? lb[kk * 800 + (2 * u + par) * 25 + p] : 0.0f;
            dst[o] = (short)bf16r(v);
        }
    } else {                            // trimmed b_out + scale-logdet constant
#pragma unroll
        for (int i = 0; i < 16; i++) {
            int idx = t + i * 256;                    // 8 layers * 512
            int l = idx >> 9, c = idx & 511, u = c >> 5, p = c & 31;
            bo_t[idx] = (p < 25) ? bout[l * 800 + (2 * u + (l & 1)) * 25 + p] : 0.0f;
        }
        lb[t] = logf(fabsf(scS[t]));                  // 8*32 = 256 values
        __syncthreads();
        for (int s = 128; s > 0; s >>= 1) { if (t < s) lb[t] += lb[t + s]; __syncthreads(); }
        if (t == 0) *sld = lb[0];
    }
}

// ---------------- flipped GEMM: A = weights (global tiles), B = activations (LDS) ----
// computes D[n][m] tiles; per wave: NSUB n-subtiles x 2 m-subtiles of 32x32
template<int KSTEPS, int NSUB>
DEVFN void gemm_flip(const short* __restrict__ wt, int ntot, int nbase,
                     const unsigned short* __restrict__ B, int bs,
                     f32x16 (&acc)[NSUB][2])
{
    const int lane = threadIdx.x & 63;
    const int l31 = lane & 31, l5 = lane >> 5;
    const bf16x8* __restrict__ w8 = (const bf16x8*)wt;
    const int wb = (nbase + l31) * 2 + l5;
    const int krow = ntot * 2;                        // bf16x8 units per kstep row
    bf16x8 a[2][NSUB];
#pragma unroll
    for (int s = 0; s < NSUB; s++) a[0][s] = w8[wb + s * 64];
#pragma unroll
    for (int s = 0; s < NSUB; s++) a[1][s] = w8[krow + wb + s * 64];
    const unsigned short* bp = B + l31 * bs + l5 * 8;
#pragma unroll
    for (int k = 0; k < KSTEPS; k++) {
        bf16x8 b0 = *(const bf16x8*)(bp + k * 16);
        bf16x8 b1 = *(const bf16x8*)(bp + 32 * bs + k * 16);
#pragma unroll
        for (int s = 0; s < NSUB; s++) {
            acc[s][0] = __builtin_amdgcn_mfma_f32_32x32x16_bf16(a[k & 1][s], b0, acc[s][0], 0, 0, 0);
            acc[s][1] = __builtin_amdgcn_mfma_f32_32x32x16_bf16(a[k & 1][s], b1, acc[s][1], 0, 0, 0);
        }
        if (k + 2 < KSTEPS) {
#pragma unroll
            for (int s = 0; s < NSUB; s++) a[k & 1][s] = w8[(size_t)(k + 2) * krow + wb + s * 64];
        }
    }
}

// MODE 0: h=v+b   1: t=relu(v+b)   2: h+=relu(v+b)   3: h=relu(h+relu(v+b))
template<int MODE>
DEVFN void store_h(f32x16 v, unsigned short* buf, int m0, int n0, const float* __restrict__ bias)
{
    const int lane = threadIdx.x & 63;
    const int m = m0 + (lane & 31);
    const int q = lane >> 5;
#pragma unroll
    for (int g = 0; g < 4; g++) {
        int n = n0 + 8 * g + 4 * q;
        float4 bb = *(const float4*)(bias + n);
        float r0 = v[4*g] + bb.x, r1 = v[4*g+1] + bb.y, r2 = v[4*g+2] + bb.z, r3 = v[4*g+3] + bb.w;
        if (MODE >= 1) { r0 = fmaxf(r0, 0.f); r1 = fmaxf(r1, 0.f); r2 = fmaxf(r2, 0.f); r3 = fmaxf(r3, 0.f); }
        unsigned short* dst = buf + m * HS + n;
        if (MODE >= 2) {
            uint2 old = *(const uint2*)dst;
            r0 += bflo(old.x); r1 += bfhi(old.x);
            r2 += bflo(old.y); r3 += bfhi(old.y);
            if (MODE == 3) { r0 = fmaxf(r0, 0.f); r1 = fmaxf(r1, 0.f); r2 = fmaxf(r2, 0.f); r3 = fmaxf(r3, 0.f); }
        }
        uint2 pk;
        pk.x = (unsigned)bf16r(r0) | ((unsigned)bf16r(r1) << 16);
        pk.y = (unsigned)bf16r(r2) | ((unsigned)bf16r(r3) << 16);
        *(uint2*)dst = pk;
    }
}

DEVFN void store_p(f32x16 v, float* pbuf, int m0, int c0, const float* __restrict__ bias)
{
    const int lane = threadIdx.x & 63;
    const int m = m0 + (lane & 31);
    const int q = lane >> 5;
#pragma unroll
    for (int g = 0; g < 4; g++) {
        int c = c0 + 8 * g + 4 * q;
        float4 bb = *(const float4*)(bias + c);
        float4 o = make_float4(v[4*g] + bb.x, v[4*g+1] + bb.y, v[4*g+2] + bb.z, v[4*g+3] + bb.w);
        *(float4*)(pbuf + m * PS + c) = o;
    }
}

// ---------------- fused flow kernel: 64 rows per block ----------------
__global__ __launch_bounds__(256, 2) void flow_kernel(
    const float* __restrict__ x_in, const float* __restrict__ scS, const float* __restrict__ scB,
    const float* __restrict__ bin, const float* __restrict__ b1a, const float* __restrict__ b1b,
    const float* __restrict__ b2a, const float* __restrict__ b2b,
    const int* __restrict__ perms,
    const short* __restrict__ wt, const float* __restrict__ bo_t, const float* __restrict__ sld,
    float* __restrict__ out)
{
    __shared__ __align__(16) unsigned short hS[64 * HS];   // 33792 B
    __shared__ __align__(16) float uS[8448];               // union: mx / t / params (33792 B)
    __shared__ float xS[64 * XS];                          // 8448 B
    __shared__ float redS[256];                            // 1024 B

    const int tid = threadIdx.x;
    const int wave = tid >> 6;
    const size_t rowbase = (size_t)blockIdx.x * 64;
    unsigned short* tS  = (unsigned short*)uS;
    unsigned short* mxS = (unsigned short*)uS;
    float* pS = uS;

#pragma unroll
    for (int i = 0; i < 8; i++) {
        int g = tid + i * 256;
        xS[(g >> 5) * XS + (g & 31)] = x_in[rowbase * NFEAT + g];
    }
    float ld_acc = 0.0f;
    __syncthreads();

    const int nbase = wave * 64;

#pragma unroll 1
    for (int l = 0; l < NLAYER; l++) {
        const int par = l & 1;
        const short* wb = wt + (size_t)l * LAYER_E;

        // ---- permute + affine + masked bf16 copy ----
        {
            int j = tid & 31; int r0 = (tid >> 5) * 8;
            int pj = perms[l * 32 + j];
            float sc = scS[l * 32 + j], sh = scB[l * 32 + j];
            float vals[8];
#pragma unroll
            for (int r = 0; r < 8; r++) vals[r] = xS[(r0 + r) * XS + pj] * sc + sh;
            __syncthreads();
            int keep = ((j & 1) != par);   // mask==True features feed the conditioner
#pragma unroll
            for (int r = 0; r < 8; r++) {
                xS[(r0 + r) * XS + j] = vals[r];
                mxS[(r0 + r) * MXS + j] = keep ? bf16r(vals[r]) : (unsigned short)0;
            }
            __syncthreads();
        }
        // ---- GEMM1: h = mx @ W_in + b_in ----
        {
            f32x16 acc[2][2];
            zacc(acc[0][0]); zacc(acc[0][1]); zacc(acc[1][0]); zacc(acc[1][1]);
            gemm_flip<2, 2>(wb, 256, nbase, mxS, MXS, acc);
#pragma unroll
            for (int s = 0; s < 2; s++) {
                store_h<0>(acc[s][0], hS, 0,  nbase + s * 32, bin + l * 256);
                store_h<0>(acc[s][1], hS, 32, nbase + s * 32, bin + l * 256);
            }
            __syncthreads();
        }
        // ---- residual block 1 ----
        {
            f32x16 acc[2][2];
            zacc(acc[0][0]); zacc(acc[0][1]); zacc(acc[1][0]); zacc(acc[1][1]);
            gemm_flip<16, 2>(wb + WIN_E, 256, nbase, hS, HS, acc);
#pragma unroll
            for (int s = 0; s < 2; s++) {
                store_h<1>(acc[s][0], tS, 0,  nbase + s * 32, b1a + l * 256);
                store_h<1>(acc[s][1], tS, 32, nbase + s * 32, b1a + l * 256);
            }
            __syncthreads();
        }
        {
            f32x16 acc[2][2];
            zacc(acc[0][0]); zacc(acc[0][1]); zacc(acc[1][0]); zacc(acc[1][1]);
            gemm_flip<16, 2>(wb + WIN_E + WH_E, 256, nbase, tS, HS, acc);
#pragma unroll
            for (int s = 0; s < 2; s++) {
                store_h<2>(acc[s][0], hS, 0,  nbase + s * 32, b1b + l * 256);
                store_h<2>(acc[s][1], hS, 32, nbase + s * 32, b1b + l * 256);
            }
            __syncthreads();
        }
        // ---- residual block 2 (+ final relu folded) ----
        {
            f32x16 acc[2][2];
            zacc(acc[0][0]); zacc(acc[0][1]); zacc(acc[1][0]); zacc(acc[1][1]);
            gemm_flip<16, 2>(wb + WIN_E + 2 * WH_E, 256, nbase, hS, HS, acc);
#pragma unroll
            for (int s = 0; s < 2; s++) {
                store_h<1>(acc[s][0], tS, 0,  nbase + s * 32, b2a + l * 256);
                store_h<1>(acc[s][1], tS, 32, nbase + s * 32, b2a + l * 256);
            }
            __syncthreads();
        }
        {
            f32x16 acc[2][2];
            zacc(acc[0][0]); zacc(acc[0][1]); zacc(acc[1][0]); zacc(acc[1][1]);
            gemm_flip<16, 2>(wb + WIN_E + 3 * WH_E, 256, nbase, tS, HS, acc);
#pragma unroll
            for (int s = 0; s < 2; s++) {
                store_h<3>(acc[s][0], hS, 0,  nbase + s * 32, b2b + l * 256);
                store_h<3>(acc[s][1], hS, 32, nbase + s * 32, b2b + l * 256);
            }
            __syncthreads();
        }
        // ---- W_out in 4 chunks of 128 cols (4 unmasked features each) + spline ----
        const short* wo = wb + WIN_E + 4 * WH_E;
        for (int ch = 0; ch < 4; ch++) {
            {
                f32x16 acc[1][2];
                zacc(acc[0][0]); zacc(acc[0][1]);
                gemm_flip<16, 1>(wo, 512, ch * 128 + wave * 32, hS, HS, acc);
                const float* bb = bo_t + l * 512 + ch * 128;
                store_p(acc[0][0], pS, 0,  wave * 32, bb);
                store_p(acc[0][1], pS, 32, wave * 32, bb);
            }
            __syncthreads();
            // spline: one (row, feature) pair per thread
            {
                int m = tid & 63, ul = tid >> 6;
                int u = ch * 4 + ul;
                int n = 2 * u + par;
                float xv = xS[m * XS + n];
                const float* pp = pS + m * PS + ul * 32;
                float uw[8], uh[8], ud[9];
#pragma unroll
                for (int i = 0; i < 8; i++) uw[i] = pp[i];
#pragma unroll
                for (int i = 0; i < 8; i++) uh[i] = pp[8 + i];
#pragma unroll
                for (int i = 0; i < 9; i++) ud[i] = pp[16 + i];
                float mw = uw[0], mh = uh[0];
#pragma unroll
                for (int i = 1; i < 8; i++) { mw = fmaxf(mw, uw[i]); mh = fmaxf(mh, uh[i]); }
                float ew[8], eh[8], sw = 0.f, sh2 = 0.f;
#pragma unroll
                for (int i = 0; i < 8; i++) { ew[i] = __expf(uw[i] - mw); sw += ew[i]; }
#pragma unroll
                for (int i = 0; i < 8; i++) { eh[i] = __expf(uh[i] - mh); sh2 += eh[i]; }
                float fw = WSCALE / sw, fh = WSCALE / sh2;
                float w[8], hh[8];
#pragma unroll
                for (int i = 0; i < 8; i++) { w[i] = ew[i] * fw + MIN_BIN; hh[i] = eh[i] * fh + MIN_BIN; }
                float d[9];
#pragma unroll
                for (int i = 0; i < 9; i++) d[i] = log1pf(__expf(ud[i] + SOFTPLUS_OFF)) + MIN_SLOPE;

                bool inside = (xv > -10.0f) && (xv < 10.0f);
                float xc = fminf(fmaxf(xv, -10.0f), 10.0f);
                float cx = -10.0f + w[0], cy = -10.0f + hh[0];
                float xk = -10.0f, yk = -10.0f, bw = w[0], bh = hh[0], dk = d[0], dk1 = d[1];
#pragma unroll
                for (int i = 1; i < 8; i++) {
                    bool take = (xc >= cx);
                    if (take) { xk = cx; yk = cy; bw = w[i]; bh = hh[i]; dk = d[i]; dk1 = d[i + 1]; }
                    cx += w[i]; cy += hh[i];
                }
                float s = bh / bw;
                float z = fminf(fmaxf((xc - xk) / bw, 0.0f), 1.0f);
                float zz = z * (1.0f - z);
                float denom = s + (dk1 + dk - 2.0f * s) * zz;
                float y = yk + bh * (s * z * z + dk * zz) / denom;
                float num = dk1 * z * z + 2.0f * s * zz + dk * (1.0f - z) * (1.0f - z);
                float ldv = 2.0f * __logf(s) + __logf(num) - 2.0f * __logf(denom);
                xS[m * XS + n] = inside ? y : xv;
                ld_acc += inside ? ldv : 0.0f;
            }
            __syncthreads();
        }
    }
    // ---- epilogue: logp + logdet ----
    {
        int m = tid & 63, jg = tid >> 6;
        float s2 = 0.f;
#pragma unroll
        for (int j = 0; j < 8; j++) { float v = xS[m * XS + jg * 8 + j]; s2 += v * v; }
        redS[tid] = ld_acc - 0.5f * s2;
        __syncthreads();
        if (tid < 64) {
            float tot = redS[tid] + redS[tid + 64] + redS[tid + 128] + redS[tid + 192]
                      + *sld - 29.406033062549525f;   // -0.5*N*log(2*pi)
            out[rowbase + tid] = tot;
        }
    }
}

extern "C" void kernel_launch(void* const* d_in, const int* in_sizes, int n_in,
                              void* d_out, int out_size, void* d_ws, size_t ws_size,
                              hipStream_t stream) {
    if (ws_size < WS_NEEDED) return;   // scratch too small: fail loudly (poisoned out)
    const float* x    = (const float*)d_in[0];
    const float* scS  = (const float*)d_in[1];
    const float* scB  = (const float*)d_in[2];
    const float* Win  = (const float*)d_in[3];
    const float* bin  = (const float*)d_in[4];
    const float* W1a  = (const float*)d_in[5];
    const float* b1a  = (const float*)d_in[6];
    const float* W1b  = (const float*)d_in[7];
    const float* b1b  = (const float*)d_in[8];
    const float* W2a  = (const float*)d_in[9];
    const float* b2a  = (const float*)d_in[10];
    const float* W2b  = (const float*)d_in[11];
    const float* b2b  = (const float*)d_in[12];
    const float* Wout = (const float*)d_in[13];
    const float* bout = (const float*)d_in[14];
    const int* perms  = (const int*)d_in[15];

    short* wt   = (short*)d_ws;
    float* bo_t = (float*)((char*)d_ws + WT_BYTES);
    float* sld  = bo_t + NLAYER * 512;

    prep_kernel<<<657, 256, 0, stream>>>(Win, W1a, W1b, W2a, W2b, Wout, bout, scS, wt, bo_t, sld);
    flow_kernel<<<65536 / 64, 256, 0, stream>>>(x, scS, scB, bin, b1a, b1b, b2a, b2b,
                                                perms, wt, bo_t, sld, (float*)d_out);
}

// Round 2
// 598.691 us; speedup vs baseline: 1.3786x; 1.3786x over previous
//
#include <hip/hip_runtime.h>
#include <hip/hip_bf16.h>

typedef __attribute__((ext_vector_type(8))) short bf16x8;
typedef __attribute__((ext_vector_type(16))) float f32x16;
typedef __attribute__((ext_vector_type(2))) float f32x2;

#define DEVFN __device__ __forceinline__

constexpr int NFEAT = 32, NLAYER = 8, HID = 256;
constexpr int HS  = 264;   // h/t LDS stride (bf16 elements), 16B-aligned
constexpr int MXS = 40;    // mx LDS stride
constexpr int XS  = 33;    // x LDS stride (floats)
constexpr int PS  = 132;   // params LDS stride (floats)
constexpr int WIN_E  = 2 * 256 * 16;    // 8192
constexpr int WH_E   = 16 * 256 * 16;   // 65536
constexpr int WOUT_E = 16 * 512 * 16;   // 131072
constexpr int LAYER_E = WIN_E + 4 * WH_E + WOUT_E;  // 401408 bf16 elems
constexpr size_t WT_BYTES = (size_t)LAYER_E * NLAYER * 2;  // 6422528
constexpr size_t WS_NEEDED = WT_BYTES + NLAYER * 512 * 4 + 4;

constexpr float MIN_BIN = 1e-4f, MIN_SLOPE = 1e-4f;
constexpr float SOFTPLUS_OFF = 0.5411666f;           // log(expm1(1 - MIN_SLOPE))
constexpr float WSCALE = 20.0f - 8.0f * MIN_BIN;     // (RMAX-RMIN) - K*MIN_BIN

DEVFN unsigned short bf16r(float f) {              // fp32 -> bf16, RNE
    unsigned u = __float_as_uint(f);
    u += 0x7fffu + ((u >> 16) & 1u);
    return (unsigned short)(u >> 16);
}
#if defined(__gfx950__) && __has_builtin(__builtin_amdgcn_cvt_pk_bf16_f32)
DEVFN unsigned pack2(float a, float b) {
    auto r = __builtin_amdgcn_cvt_pk_bf16_f32(a, b);
    return __builtin_bit_cast(unsigned, r);
}
#else
DEVFN unsigned pack2(float a, float b) {
    return (unsigned)bf16r(a) | ((unsigned)bf16r(b) << 16);
}
#endif
DEVFN float bflo(unsigned v) { return __uint_as_float(v << 16); }
DEVFN float bfhi(unsigned v) { return __uint_as_float(v & 0xffff0000u); }
DEVFN float frcp(float x) { return __builtin_amdgcn_rcpf(x); }
DEVFN f32x2 vmax0(f32x2 v) {
#if __has_builtin(__builtin_elementwise_max)
    return __builtin_elementwise_max(v, (f32x2){0.f, 0.f});
#else
    return (f32x2){fmaxf(v.x, 0.f), fmaxf(v.y, 0.f)};
#endif
}

// ---------------- prep kernel: bf16 transposed weight tiles in ws ----------------
// wt layout per matrix: [kstep][n][16kk] with element = W[k=kstep*16+kk][n]
__global__ __launch_bounds__(256) void prep_kernel(
    const float* __restrict__ Win, const float* __restrict__ W1a, const float* __restrict__ W1b,
    const float* __restrict__ W2a, const float* __restrict__ W2b, const float* __restrict__ Wout,
    const float* __restrict__ bout, const float* __restrict__ scS,
    short* __restrict__ wt, float* __restrict__ bo_t, float* __restrict__ sld)
{
    __shared__ float lb[16 * 800];
    const int b = blockIdx.x, t = threadIdx.x;
    if (b < 16) {                       // W_in: (L,32,256), k-dim = 32 -> 2 ksteps
        int l = b >> 1, ks = b & 1;
        const float* src = Win + l * 32 * 256 + ks * 16 * 256;
#pragma unroll
        for (int i = 0; i < 16; i++) { int idx = t + i * 256; lb[idx] = src[idx]; }
        __syncthreads();
        short* dst = wt + (size_t)l * LAYER_E + ks * 4096;
#pragma unroll
        for (int i = 0; i < 16; i++) {
            int o = t + i * 256; int n = o >> 4, kk = o & 15;
            dst[o] = (short)bf16r(lb[kk * 256 + n]);
        }
    } else if (b < 528) {               // W1a/W1b/W2a/W2b: 256x256, 16 ksteps each
        int id = b - 16; int l = id >> 6, mat = (id >> 4) & 3, ks = id & 15;
        const float* mats[4] = {W1a, W1b, W2a, W2b};
        const float* src = mats[mat] + l * 65536 + ks * 16 * 256;
#pragma unroll
        for (int i = 0; i < 16; i++) { int idx = t + i * 256; lb[idx] = src[idx]; }
        __syncthreads();
        short* dst = wt + (size_t)l * LAYER_E + WIN_E + mat * WH_E + ks * 4096;
#pragma unroll
        for (int i = 0; i < 16; i++) {
            int o = t + i * 256; int n = o >> 4, kk = o & 15;
            dst[o] = (short)bf16r(lb[kk * 256 + n]);
        }
    } else if (b < 656) {               // W_out: trim to unmasked cols, pad 25->32
        int id = b - 528; int l = id >> 4, ks = id & 15; int par = l & 1;
        const float* src = Wout + (size_t)l * 256 * 800 + ks * 16 * 800;
        for (int k = 0; k < 16; k++)
            for (int c = t; c < 800; c += 256) lb[k * 800 + c] = src[k * 800 + c];
        __syncthreads();
        short* dst = wt + (size_t)l * LAYER_E + WIN_E + 4 * WH_E + ks * 8192;
#pragma unroll
        for (int i = 0; i < 32; i++) {
            int o = t + i * 256; int c = o >> 4, kk = o & 15;
            int u = c >> 5, p = c & 31;
            float v = (p < 25) ? lb[kk * 800 + (2 * u + par) * 25 + p] : 0.0f;
            dst[o] = (short)bf16r(v);
        }
    } else {                            // trimmed b_out + scale-logdet constant
#pragma unroll
        for (int i = 0; i < 16; i++) {
            int idx = t + i * 256;                    // 8 layers * 512
            int l = idx >> 9, c = idx & 511, u = c >> 5, p = c & 31;
            bo_t[idx] = (p < 25) ? bout[l * 800 + (2 * u + (l & 1)) * 25 + p] : 0.0f;
        }
        lb[t] = logf(fabsf(scS[t]));                  // 8*32 = 256 values
        __syncthreads();
        for (int s = 128; s > 0; s >>= 1) { if (t < s) lb[t] += lb[t + s]; __syncthreads(); }
        if (t == 0) *sld = lb[0];
    }
}

// ---------------- flipped GEMM: A = weights (global tiles), B = activations (LDS) ----
// computes D[n][m] tiles; per wave: NSUB n-subtiles x 2 m-subtiles of 32x32
template<int KSTEPS, int NSUB>
DEVFN void gemm_flip(const short* __restrict__ wt, int ntot, int nbase,
                     const unsigned short* __restrict__ B, int bs,
                     f32x16 (&acc)[NSUB][2])
{
    constexpr int D = (KSTEPS < 4) ? KSTEPS : 4;    // prefetch ring depth
    const int lane = threadIdx.x & 63;
    const int l31 = lane & 31, l5 = lane >> 5;
    const bf16x8* __restrict__ w8 = (const bf16x8*)wt;
    const int wb = (nbase + l31) * 2 + l5;
    const int krow = ntot * 2;                        // bf16x8 units per kstep row
    bf16x8 a[D][NSUB];
#pragma unroll
    for (int p = 0; p < D; p++)
#pragma unroll
        for (int s = 0; s < NSUB; s++) a[p][s] = w8[(size_t)p * krow + wb + s * 64];
    const unsigned short* bp = B + l31 * bs + l5 * 8;
#pragma unroll
    for (int k = 0; k < KSTEPS; k++) {
        bf16x8 b0 = *(const bf16x8*)(bp + k * 16);
        bf16x8 b1 = *(const bf16x8*)(bp + 32 * bs + k * 16);
#pragma unroll
        for (int s = 0; s < NSUB; s++) {
            acc[s][0] = __builtin_amdgcn_mfma_f32_32x32x16_bf16(a[k % D][s], b0, acc[s][0], 0, 0, 0);
            acc[s][1] = __builtin_amdgcn_mfma_f32_32x32x16_bf16(a[k % D][s], b1, acc[s][1], 0, 0, 0);
        }
        if (k + D < KSTEPS) {
#pragma unroll
            for (int s = 0; s < NSUB; s++) a[k % D][s] = w8[(size_t)(k + D) * krow + wb + s * 64];
        }
    }
}

// acc init from bias (bias pre-added so epilogue is pure pack/store)
// D-layout row = (reg&3) + 8*(reg>>2) + 4*(lane>>5); bias points at column base n0
DEVFN void binit(f32x16& a, const float* __restrict__ bias)
{
    const int q = (threadIdx.x >> 5) & 1;
    const float* bp = bias + 4 * q;
#pragma unroll
    for (int g = 0; g < 4; g++) {
        float4 b = *(const float4*)(bp + 8 * g);
        a[4*g+0] = b.x; a[4*g+1] = b.y; a[4*g+2] = b.z; a[4*g+3] = b.w;
    }
}

// MODE 0: h=v   1: t=relu(v)   2: h+=relu(v)   3: h=relu(h+relu(v))   (bias already in v)
template<int MODE>
DEVFN void store_h(const f32x16& v, unsigned short* buf, int m0, int n0)
{
    const int lane = threadIdx.x & 63;
    const int m = m0 + (lane & 31);
    const int q = lane >> 5;
    unsigned short* rowp = buf + m * HS + n0 + 4 * q;
#pragma unroll
    for (int g = 0; g < 4; g++) {
        f32x2 r0 = {v[4*g+0], v[4*g+1]};
        f32x2 r1 = {v[4*g+2], v[4*g+3]};
        if (MODE >= 1) { r0 = vmax0(r0); r1 = vmax0(r1); }
        unsigned short* dst = rowp + 8 * g;
        if (MODE >= 2) {
            uint2 old = *(const uint2*)dst;
            r0 += (f32x2){bflo(old.x), bfhi(old.x)};
            r1 += (f32x2){bflo(old.y), bfhi(old.y)};
            if (MODE == 3) { r0 = vmax0(r0); r1 = vmax0(r1); }
        }
        uint2 pk;
        pk.x = pack2(r0.x, r0.y);
        pk.y = pack2(r1.x, r1.y);
        *(uint2*)dst = pk;
    }
}

DEVFN void store_p(const f32x16& v, float* pbuf, int m0, int c0)
{
    const int lane = threadIdx.x & 63;
    const int m = m0 + (lane & 31);
    const int q = lane >> 5;
    float* rowp = pbuf + m * PS + c0 + 4 * q;
#pragma unroll
    for (int g = 0; g < 4; g++)
        *(float4*)(rowp + 8 * g) = make_float4(v[4*g], v[4*g+1], v[4*g+2], v[4*g+3]);
}

// ---------------- fused flow kernel: 64 rows per block ----------------
__global__ __launch_bounds__(256, 2) void flow_kernel(
    const float* __restrict__ x_in, const float* __restrict__ scS, const float* __restrict__ scB,
    const float* __restrict__ bin, const float* __restrict__ b1a, const float* __restrict__ b1b,
    const float* __restrict__ b2a, const float* __restrict__ b2b,
    const int* __restrict__ perms,
    const short* __restrict__ wt, const float* __restrict__ bo_t, const float* __restrict__ sld,
    float* __restrict__ out)
{
    __shared__ __align__(16) unsigned short hS[64 * HS];   // 33792 B
    __shared__ __align__(16) float uS[8448];               // union: mx / t / params (33792 B)
    __shared__ float xS[64 * XS];                          // 8448 B
    __shared__ float redS[256];                            // 1024 B

    const int tid = threadIdx.x;
    const int wave = tid >> 6;
    const size_t rowbase = (size_t)blockIdx.x * 64;
    unsigned short* tS  = (unsigned short*)uS;
    unsigned short* mxS = (unsigned short*)uS;
    float* pS = uS;

#pragma unroll
    for (int i = 0; i < 8; i++) {
        int g = tid + i * 256;
        xS[(g >> 5) * XS + (g & 31)] = x_in[rowbase * NFEAT + g];
    }
    float ld_acc = 0.0f;
    __syncthreads();

    const int nbase = wave * 64;

#pragma unroll 1
    for (int l = 0; l < NLAYER; l++) {
        const int par = l & 1;
        const short* wb = wt + (size_t)l * LAYER_E;

        // ---- permute + affine + masked bf16 copy ----
        {
            int j = tid & 31; int r0 = (tid >> 5) * 8;
            int pj = perms[l * 32 + j];
            float sc = scS[l * 32 + j], sh = scB[l * 32 + j];
            float vals[8];
#pragma unroll
            for (int r = 0; r < 8; r++) vals[r] = xS[(r0 + r) * XS + pj] * sc + sh;
            __syncthreads();
            int keep = ((j & 1) != par);   // mask==True features feed the conditioner
#pragma unroll
            for (int r = 0; r < 8; r++) {
                xS[(r0 + r) * XS + j] = vals[r];
                mxS[(r0 + r) * MXS + j] = keep ? bf16r(vals[r]) : (unsigned short)0;
            }
            __syncthreads();
        }
        // ---- GEMM1: h = mx @ W_in + b_in ----
        {
            f32x16 acc[2][2];
            binit(acc[0][0], bin + l * 256 + nbase);      binit(acc[0][1], bin + l * 256 + nbase);
            binit(acc[1][0], bin + l * 256 + nbase + 32); binit(acc[1][1], bin + l * 256 + nbase + 32);
            gemm_flip<2, 2>(wb, 256, nbase, mxS, MXS, acc);
#pragma unroll
            for (int s = 0; s < 2; s++) {
                store_h<0>(acc[s][0], hS, 0,  nbase + s * 32);
                store_h<0>(acc[s][1], hS, 32, nbase + s * 32);
            }
            __syncthreads();
        }
        // ---- residual block 1 ----
        {
            f32x16 acc[2][2];
            binit(acc[0][0], b1a + l * 256 + nbase);      binit(acc[0][1], b1a + l * 256 + nbase);
            binit(acc[1][0], b1a + l * 256 + nbase + 32); binit(acc[1][1], b1a + l * 256 + nbase + 32);
            gemm_flip<16, 2>(wb + WIN_E, 256, nbase, hS, HS, acc);
#pragma unroll
            for (int s = 0; s < 2; s++) {
                store_h<1>(acc[s][0], tS, 0,  nbase + s * 32);
                store_h<1>(acc[s][1], tS, 32, nbase + s * 32);
            }
            __syncthreads();
        }
        {
            f32x16 acc[2][2];
            binit(acc[0][0], b1b + l * 256 + nbase);      binit(acc[0][1], b1b + l * 256 + nbase);
            binit(acc[1][0], b1b + l * 256 + nbase + 32); binit(acc[1][1], b1b + l * 256 + nbase + 32);
            gemm_flip<16, 2>(wb + WIN_E + WH_E, 256, nbase, tS, HS, acc);
#pragma unroll
            for (int s = 0; s < 2; s++) {
                store_h<2>(acc[s][0], hS, 0,  nbase + s * 32);
                store_h<2>(acc[s][1], hS, 32, nbase + s * 32);
            }
            __syncthreads();
        }
        // ---- residual block 2 (+ final relu folded) ----
        {
            f32x16 acc[2][2];
            binit(acc[0][0], b2a + l * 256 + nbase);      binit(acc[0][1], b2a + l * 256 + nbase);
            binit(acc[1][0], b2a + l * 256 + nbase + 32); binit(acc[1][1], b2a + l * 256 + nbase + 32);
            gemm_flip<16, 2>(wb + WIN_E + 2 * WH_E, 256, nbase, hS, HS, acc);
#pragma unroll
            for (int s = 0; s < 2; s++) {
                store_h<1>(acc[s][0], tS, 0,  nbase + s * 32);
                store_h<1>(acc[s][1], tS, 32, nbase + s * 32);
            }
            __syncthreads();
        }
        {
            f32x16 acc[2][2];
            binit(acc[0][0], b2b + l * 256 + nbase);      binit(acc[0][1], b2b + l * 256 + nbase);
            binit(acc[1][0], b2b + l * 256 + nbase + 32); binit(acc[1][1], b2b + l * 256 + nbase + 32);
            gemm_flip<16, 2>(wb + WIN_E + 3 * WH_E, 256, nbase, tS, HS, acc);
#pragma unroll
            for (int s = 0; s < 2; s++) {
                store_h<3>(acc[s][0], hS, 0,  nbase + s * 32);
                store_h<3>(acc[s][1], hS, 32, nbase + s * 32);
            }
            __syncthreads();
        }
        // ---- W_out in 4 chunks of 128 cols (4 unmasked features each) + spline ----
        const short* wo = wb + WIN_E + 4 * WH_E;
        for (int ch = 0; ch < 4; ch++) {
            {
                f32x16 acc[1][2];
                const float* bb = bo_t + l * 512 + ch * 128 + wave * 32;
                binit(acc[0][0], bb); binit(acc[0][1], bb);
                gemm_flip<16, 1>(wo, 512, ch * 128 + wave * 32, hS, HS, acc);
                store_p(acc[0][0], pS, 0,  wave * 32);
                store_p(acc[0][1], pS, 32, wave * 32);
            }
            __syncthreads();
            // spline: one (row, feature) pair per thread
            {
                int m = tid & 63, ul = tid >> 6;
                int n = 2 * (ch * 4 + ul) + par;
                float xv = xS[m * XS + n];
                const float* pp = pS + m * PS + ul * 32;
                float4 p0 = *(const float4*)(pp);
                float4 p1 = *(const float4*)(pp + 4);
                float4 p2 = *(const float4*)(pp + 8);
                float4 p3 = *(const float4*)(pp + 12);
                float4 p4 = *(const float4*)(pp + 16);
                float4 p5 = *(const float4*)(pp + 20);
                float p24 = pp[24];
                float uw[8] = {p0.x, p0.y, p0.z, p0.w, p1.x, p1.y, p1.z, p1.w};
                float uh[8] = {p2.x, p2.y, p2.z, p2.w, p3.x, p3.y, p3.z, p3.w};
                float ud[9] = {p4.x, p4.y, p4.z, p4.w, p5.x, p5.y, p5.z, p5.w, p24};

                float ew[8], eh[8], sw = 0.f, sh2 = 0.f;
#pragma unroll
                for (int i = 0; i < 8; i++) { ew[i] = __expf(uw[i]); sw += ew[i]; }
#pragma unroll
                for (int i = 0; i < 8; i++) { eh[i] = __expf(uh[i]); sh2 += eh[i]; }
                float fw = WSCALE * frcp(sw), fh = WSCALE * frcp(sh2);
                float w[8], hh[8];
#pragma unroll
                for (int i = 0; i < 8; i++) { w[i] = fmaf(ew[i], fw, MIN_BIN); hh[i] = fmaf(eh[i], fh, MIN_BIN); }

                bool inside = (xv > -10.0f) && (xv < 10.0f);
                float xc = fminf(fmaxf(xv, -10.0f), 10.0f);
                float cx = -10.0f + w[0], cy = -10.0f + hh[0];
                float xk = -10.0f, yk = -10.0f, bw = w[0], bh = hh[0];
                float udk = ud[0], udk1 = ud[1];
#pragma unroll
                for (int i = 1; i < 8; i++) {
                    bool take = (xc >= cx);
                    if (take) { xk = cx; yk = cy; bw = w[i]; bh = hh[i]; udk = ud[i]; udk1 = ud[i + 1]; }
                    cx += w[i]; cy += hh[i];
                }
                float dk  = __logf(1.f + __expf(udk  + SOFTPLUS_OFF)) + MIN_SLOPE;
                float dk1 = __logf(1.f + __expf(udk1 + SOFTPLUS_OFF)) + MIN_SLOPE;
                float ibw = frcp(bw);
                float s = bh * ibw;
                float z = fminf(fmaxf((xc - xk) * ibw, 0.0f), 1.0f);
                float omz = 1.0f - z;
                float zz = z * omz;
                float denom = fmaf(dk1 + dk - 2.0f * s, zz, s);
                float idenom = frcp(denom);
                float y = fmaf(bh * fmaf(s * z, z, dk * zz), idenom, yk);
                float num = fmaf(dk1 * z, z, fmaf(2.0f * s, zz, dk * omz * omz));
                float ldv = 2.0f * __logf(s * idenom) + __logf(num);
                xS[m * XS + n] = inside ? y : xv;
                ld_acc += inside ? ldv : 0.0f;
            }
            __syncthreads();
        }
    }
    // ---- epilogue: logp + logdet ----
    {
        int m = tid & 63, jg = tid >> 6;
        float s2 = 0.f;
#pragma unroll
        for (int j = 0; j < 8; j++) { float v = xS[m * XS + jg * 8 + j]; s2 += v * v; }
        redS[tid] = ld_acc - 0.5f * s2;
        __syncthreads();
        if (tid < 64) {
            float tot = redS[tid] + redS[tid + 64] + redS[tid + 128] + redS[tid + 192]
                      + *sld - 29.406033062549525f;   // -0.5*N*log(2*pi)
            out[rowbase + tid] = tot;
        }
    }
}

extern "C" void kernel_launch(void* const* d_in, const int* in_sizes, int n_in,
                              void* d_out, int out_size, void* d_ws, size_t ws_size,
                              hipStream_t stream) {
    if (ws_size < WS_NEEDED) return;   // scratch too small: fail loudly (poisoned out)
    const float* x    = (const float*)d_in[0];
    const float* scS  = (const float*)d_in[1];
    const float* scB  = (const float*)d_in[2];
    const float* Win  = (const float*)d_in[3];
    const float* bin  = (const float*)d_in[4];
    const float* W1a  = (const float*)d_in[5];
    const float* b1a  = (const float*)d_in[6];
    const float* W1b  = (const float*)d_in[7];
    const float* b1b  = (const float*)d_in[8];
    const float* W2a  = (const float*)d_in[9];
    const float* b2a  = (const float*)d_in[10];
    const float* W2b  = (const float*)d_in[11];
    const float* b2b  = (const float*)d_in[12];
    const float* Wout = (const float*)d_in[13];
    const float* bout = (const float*)d_in[14];
    const int* perms  = (const int*)d_in[15];

    short* wt   = (short*)d_ws;
    float* bo_t = (float*)((char*)d_ws + WT_BYTES);
    float* sld  = bo_t + NLAYER * 512;

    prep_kernel<<<657, 256, 0, stream>>>(Win, W1a, W1b, W2a, W2b, Wout, bout, scS, wt, bo_t, sld);
    flow_kernel<<<65536 / 64, 256, 0, stream>>>(x, scS, scB, bin, b1a, b1b, b2a, b2b,
                                                perms, wt, bo_t, sld, (float*)d_out);
}

// Round 3
// 573.878 us; speedup vs baseline: 1.4382x; 1.0432x over previous
//
#include <hip/hip_runtime.h>
#include <hip/hip_bf16.h>

typedef __attribute__((ext_vector_type(8))) short bf16x8;
typedef __attribute__((ext_vector_type(16))) float f32x16;
typedef __attribute__((ext_vector_type(2))) float f32x2;

#define DEVFN __device__ __forceinline__

constexpr int NFEAT = 32, NLAYER = 8, HID = 256;
constexpr int HS  = 264;   // h/t LDS stride (bf16 elements), 16B-aligned
constexpr int MXS = 40;    // mx LDS stride
constexpr int XS  = 33;    // x LDS stride (floats)
constexpr int WIN_E  = 2 * 256 * 16;    // 8192
constexpr int WH_E   = 16 * 256 * 16;   // 65536
constexpr int WOUT_E = 16 * 512 * 16;   // 131072
constexpr int LAYER_E = WIN_E + 4 * WH_E + WOUT_E;  // 401408 bf16 elems
constexpr size_t WT_BYTES = (size_t)LAYER_E * NLAYER * 2;  // 6422528
constexpr size_t WS_NEEDED = WT_BYTES + NLAYER * 512 * 4 + 4;

constexpr float MIN_BIN = 1e-4f, MIN_SLOPE = 1e-4f;
constexpr float SOFTPLUS_OFF = 0.5411666f;           // log(expm1(1 - MIN_SLOPE))
constexpr float WSCALE = 20.0f - 8.0f * MIN_BIN;     // (RMAX-RMIN) - K*MIN_BIN

DEVFN unsigned short bf16r(float f) {              // fp32 -> bf16, RNE
    unsigned u = __float_as_uint(f);
    u += 0x7fffu + ((u >> 16) & 1u);
    return (unsigned short)(u >> 16);
}
#if defined(__gfx950__) && __has_builtin(__builtin_amdgcn_cvt_pk_bf16_f32)
DEVFN unsigned pack2(float a, float b) {
    auto r = __builtin_amdgcn_cvt_pk_bf16_f32(a, b);
    return __builtin_bit_cast(unsigned, r);
}
#else
DEVFN unsigned pack2(float a, float b) {
    return (unsigned)bf16r(a) | ((unsigned)bf16r(b) << 16);
}
#endif
DEVFN float bflo(unsigned v) { return __uint_as_float(v << 16); }
DEVFN float bfhi(unsigned v) { return __uint_as_float(v & 0xffff0000u); }
DEVFN float frcp(float x) { return __builtin_amdgcn_rcpf(x); }
DEVFN f32x2 vmax0(f32x2 v) {
#if __has_builtin(__builtin_elementwise_max)
    return __builtin_elementwise_max(v, (f32x2){0.f, 0.f});
#else
    return (f32x2){fmaxf(v.x, 0.f), fmaxf(v.y, 0.f)};
#endif
}

// ---------------- prep kernel: bf16 transposed weight tiles in ws ----------------
// wt layout per matrix: [kstep][n][16kk] with element = W[k=kstep*16+kk][n]
__global__ __launch_bounds__(256) void prep_kernel(
    const float* __restrict__ Win, const float* __restrict__ W1a, const float* __restrict__ W1b,
    const float* __restrict__ W2a, const float* __restrict__ W2b, const float* __restrict__ Wout,
    const float* __restrict__ bout, const float* __restrict__ scS,
    short* __restrict__ wt, float* __restrict__ bo_t, float* __restrict__ sld)
{
    __shared__ float lb[16 * 800];
    const int b = blockIdx.x, t = threadIdx.x;
    if (b < 16) {                       // W_in: (L,32,256), k-dim = 32 -> 2 ksteps
        int l = b >> 1, ks = b & 1;
        const float* src = Win + l * 32 * 256 + ks * 16 * 256;
#pragma unroll
        for (int i = 0; i < 16; i++) { int idx = t + i * 256; lb[idx] = src[idx]; }
        __syncthreads();
        short* dst = wt + (size_t)l * LAYER_E + ks * 4096;
#pragma unroll
        for (int i = 0; i < 16; i++) {
            int o = t + i * 256; int n = o >> 4, kk = o & 15;
            dst[o] = (short)bf16r(lb[kk * 256 + n]);
        }
    } else if (b < 528) {               // W1a/W1b/W2a/W2b: 256x256, 16 ksteps each
        int id = b - 16; int l = id >> 6, mat = (id >> 4) & 3, ks = id & 15;
        const float* mats[4] = {W1a, W1b, W2a, W2b};
        const float* src = mats[mat] + l * 65536 + ks * 16 * 256;
#pragma unroll
        for (int i = 0; i < 16; i++) { int idx = t + i * 256; lb[idx] = src[idx]; }
        __syncthreads();
        short* dst = wt + (size_t)l * LAYER_E + WIN_E + mat * WH_E + ks * 4096;
#pragma unroll
        for (int i = 0; i < 16; i++) {
            int o = t + i * 256; int n = o >> 4, kk = o & 15;
            dst[o] = (short)bf16r(lb[kk * 256 + n]);
        }
    } else if (b < 656) {               // W_out: trim to unmasked cols, pad 25->32
        int id = b - 528; int l = id >> 4, ks = id & 15; int par = l & 1;
        const float* src = Wout + (size_t)l * 256 * 800 + ks * 16 * 800;
        for (int k = 0; k < 16; k++)
            for (int c = t; c < 800; c += 256) lb[k * 800 + c] = src[k * 800 + c];
        __syncthreads();
        short* dst = wt + (size_t)l * LAYER_E + WIN_E + 4 * WH_E + ks * 8192;
#pragma unroll
        for (int i = 0; i < 32; i++) {
            int o = t + i * 256; int c = o >> 4, kk = o & 15;
            int u = c >> 5, p = c & 31;
            float v = (p < 25) ? lb[kk * 800 + (2 * u + par) * 25 + p] : 0.0f;
            dst[o] = (short)bf16r(v);
        }
    } else {                            // trimmed b_out + scale-logdet constant
#pragma unroll
        for (int i = 0; i < 16; i++) {
            int idx = t + i * 256;                    // 8 layers * 512
            int l = idx >> 9, c = idx & 511, u = c >> 5, p = c & 31;
            bo_t[idx] = (p < 25) ? bout[l * 800 + (2 * u + (l & 1)) * 25 + p] : 0.0f;
        }
        lb[t] = logf(fabsf(scS[t]));                  // 8*32 = 256 values
        __syncthreads();
        for (int s = 128; s > 0; s >>= 1) { if (t < s) lb[t] += lb[t + s]; __syncthreads(); }
        if (t == 0) *sld = lb[0];
    }
}

// ---------------- flipped GEMM: A = weights (global tiles), B = activations (LDS) ----
// computes D[n][m] tiles; per wave: NSUB n-subtiles x 2 m-subtiles of 32x32
template<int KSTEPS, int NSUB, int DEPTH>
DEVFN void gemm_flip(const short* __restrict__ wt, int ntot, int nbase,
                     const unsigned short* __restrict__ B, int bs,
                     f32x16 (&acc)[NSUB][2])
{
    constexpr int D = (KSTEPS < DEPTH) ? KSTEPS : DEPTH;    // prefetch ring depth
    const int lane = threadIdx.x & 63;
    const int l31 = lane & 31, l5 = lane >> 5;
    const bf16x8* __restrict__ w8 = (const bf16x8*)wt;
    const int wb = (nbase + l31) * 2 + l5;
    const int krow = ntot * 2;                        // bf16x8 units per kstep row
    bf16x8 a[D][NSUB];
#pragma unroll
    for (int p = 0; p < D; p++)
#pragma unroll
        for (int s = 0; s < NSUB; s++) a[p][s] = w8[(size_t)p * krow + wb + s * 64];
    const unsigned short* bp = B + l31 * bs + l5 * 8;
#pragma unroll
    for (int k = 0; k < KSTEPS; k++) {
        bf16x8 b0 = *(const bf16x8*)(bp + k * 16);
        bf16x8 b1 = *(const bf16x8*)(bp + 32 * bs + k * 16);
#pragma unroll
        for (int s = 0; s < NSUB; s++) {
            acc[s][0] = __builtin_amdgcn_mfma_f32_32x32x16_bf16(a[k % D][s], b0, acc[s][0], 0, 0, 0);
            acc[s][1] = __builtin_amdgcn_mfma_f32_32x32x16_bf16(a[k % D][s], b1, acc[s][1], 0, 0, 0);
        }
        if (k + D < KSTEPS) {
#pragma unroll
            for (int s = 0; s < NSUB; s++) a[k % D][s] = w8[(size_t)(k + D) * krow + wb + s * 64];
        }
    }
}

// acc init from bias (bias pre-added so epilogue is pure pack/store)
// D-layout row = (reg&3) + 8*(reg>>2) + 4*(lane>>5); bias points at column base n0
DEVFN void binit(f32x16& a, const float* __restrict__ bias)
{
    const int q = (threadIdx.x >> 5) & 1;
    const float* bp = bias + 4 * q;
#pragma unroll
    for (int g = 0; g < 4; g++) {
        float4 b = *(const float4*)(bp + 8 * g);
        a[4*g+0] = b.x; a[4*g+1] = b.y; a[4*g+2] = b.z; a[4*g+3] = b.w;
    }
}

// MODE 0: h=v   1: t=relu(v)   2: h+=relu(v)   3: h=relu(h+relu(v))   (bias already in v)
template<int MODE>
DEVFN void store_h(const f32x16& v, unsigned short* buf, int m0, int n0)
{
    const int lane = threadIdx.x & 63;
    const int m = m0 + (lane & 31);
    const int q = lane >> 5;
    unsigned short* rowp = buf + m * HS + n0 + 4 * q;
#pragma unroll
    for (int g = 0; g < 4; g++) {
        f32x2 r0 = {v[4*g+0], v[4*g+1]};
        f32x2 r1 = {v[4*g+2], v[4*g+3]};
        if (MODE >= 1) { r0 = vmax0(r0); r1 = vmax0(r1); }
        unsigned short* dst = rowp + 8 * g;
        if (MODE >= 2) {
            uint2 old = *(const uint2*)dst;
            r0 += (f32x2){bflo(old.x), bfhi(old.x)};
            r1 += (f32x2){bflo(old.y), bfhi(old.y)};
            if (MODE == 3) { r0 = vmax0(r0); r1 = vmax0(r1); }
        }
        uint2 pk;
        pk.x = pack2(r0.x, r0.y);
        pk.y = pack2(r1.x, r1.y);
        *(uint2*)dst = pk;
    }
}

// ---------------- fused flow kernel: 64 rows per block ----------------
__global__ __launch_bounds__(256, 2) void flow_kernel(
    const float* __restrict__ x_in, const float* __restrict__ scS, const float* __restrict__ scB,
    const float* __restrict__ bin, const float* __restrict__ b1a, const float* __restrict__ b1b,
    const float* __restrict__ b2a, const float* __restrict__ b2b,
    const int* __restrict__ perms,
    const short* __restrict__ wt, const float* __restrict__ bo_t, const float* __restrict__ sld,
    float* __restrict__ out)
{
    __shared__ __align__(16) unsigned short hS[64 * HS];   // 33792 B
    __shared__ __align__(16) unsigned short uS[64 * HS];   // union: mx / t (33792 B)
    __shared__ float xS[64 * XS];                          // 8448 B
    __shared__ float redS[256];                            // 1024 B

    const int tid = threadIdx.x;
    const int wave = tid >> 6;
    const int lane = tid & 63;
    const int q = lane >> 5;
    const size_t rowbase = (size_t)blockIdx.x * 64;
    unsigned short* tS  = uS;
    unsigned short* mxS = uS;

#pragma unroll
    for (int i = 0; i < 8; i++) {
        int g = tid + i * 256;
        xS[(g >> 5) * XS + (g & 31)] = x_in[rowbase * NFEAT + g];
    }
    float ld_acc = 0.0f;
    __syncthreads();

    const int nbase = wave * 64;

#pragma unroll 1
    for (int l = 0; l < NLAYER; l++) {
        const int par = l & 1;
        const short* wb = wt + (size_t)l * LAYER_E;

        // ---- permute + affine + masked bf16 copy ----
        {
            int j = tid & 31; int r0 = (tid >> 5) * 8;
            int pj = perms[l * 32 + j];
            float sc = scS[l * 32 + j], sh = scB[l * 32 + j];
            float vals[8];
#pragma unroll
            for (int r = 0; r < 8; r++) vals[r] = xS[(r0 + r) * XS + pj] * sc + sh;
            __syncthreads();
            int keep = ((j & 1) != par);   // mask==True features feed the conditioner
#pragma unroll
            for (int r = 0; r < 8; r++) {
                xS[(r0 + r) * XS + j] = vals[r];
                mxS[(r0 + r) * MXS + j] = keep ? bf16r(vals[r]) : (unsigned short)0;
            }
            __syncthreads();
        }
        // ---- GEMM1: h = mx @ W_in + b_in ----
        {
            f32x16 acc[2][2];
            binit(acc[0][0], bin + l * 256 + nbase);      binit(acc[0][1], bin + l * 256 + nbase);
            binit(acc[1][0], bin + l * 256 + nbase + 32); binit(acc[1][1], bin + l * 256 + nbase + 32);
            gemm_flip<2, 2, 2>(wb, 256, nbase, mxS, MXS, acc);
#pragma unroll
            for (int s = 0; s < 2; s++) {
                store_h<0>(acc[s][0], hS, 0,  nbase + s * 32);
                store_h<0>(acc[s][1], hS, 32, nbase + s * 32);
            }
            __syncthreads();
        }
        // ---- residual block 1 ----
        {
            f32x16 acc[2][2];
            binit(acc[0][0], b1a + l * 256 + nbase);      binit(acc[0][1], b1a + l * 256 + nbase);
            binit(acc[1][0], b1a + l * 256 + nbase + 32); binit(acc[1][1], b1a + l * 256 + nbase + 32);
            gemm_flip<16, 2, 4>(wb + WIN_E, 256, nbase, hS, HS, acc);
#pragma unroll
            for (int s = 0; s < 2; s++) {
                store_h<1>(acc[s][0], tS, 0,  nbase + s * 32);
                store_h<1>(acc[s][1], tS, 32, nbase + s * 32);
            }
            __syncthreads();
        }
        {
            f32x16 acc[2][2];
            binit(acc[0][0], b1b + l * 256 + nbase);      binit(acc[0][1], b1b + l * 256 + nbase);
            binit(acc[1][0], b1b + l * 256 + nbase + 32); binit(acc[1][1], b1b + l * 256 + nbase + 32);
            gemm_flip<16, 2, 4>(wb + WIN_E + WH_E, 256, nbase, tS, HS, acc);
#pragma unroll
            for (int s = 0; s < 2; s++) {
                store_h<2>(acc[s][0], hS, 0,  nbase + s * 32);
                store_h<2>(acc[s][1], hS, 32, nbase + s * 32);
            }
            __syncthreads();
        }
        // ---- residual block 2 (+ final relu folded) ----
        {
            f32x16 acc[2][2];
            binit(acc[0][0], b2a + l * 256 + nbase);      binit(acc[0][1], b2a + l * 256 + nbase);
            binit(acc[1][0], b2a + l * 256 + nbase + 32); binit(acc[1][1], b2a + l * 256 + nbase + 32);
            gemm_flip<16, 2, 4>(wb + WIN_E + 2 * WH_E, 256, nbase, hS, HS, acc);
#pragma unroll
            for (int s = 0; s < 2; s++) {
                store_h<1>(acc[s][0], tS, 0,  nbase + s * 32);
                store_h<1>(acc[s][1], tS, 32, nbase + s * 32);
            }
            __syncthreads();
        }
        {
            f32x16 acc[2][2];
            binit(acc[0][0], b2b + l * 256 + nbase);      binit(acc[0][1], b2b + l * 256 + nbase);
            binit(acc[1][0], b2b + l * 256 + nbase + 32); binit(acc[1][1], b2b + l * 256 + nbase + 32);
            gemm_flip<16, 2, 4>(wb + WIN_E + 3 * WH_E, 256, nbase, tS, HS, acc);
#pragma unroll
            for (int s = 0; s < 2; s++) {
                store_h<3>(acc[s][0], hS, 0,  nbase + s * 32);
                store_h<3>(acc[s][1], hS, 32, nbase + s * 32);
            }
            __syncthreads();
        }
        // ---- W_out single pass: wave w owns cols [128w,128w+128) = features 4w..4w+3 ----
        // then in-register half-exchange (lane^32) -> full 32-param vector per (row=lane, u)
        {
            const short* wo = wb + WIN_E + 4 * WH_E;
            f32x16 acc[4][2];
            const float* bb = bo_t + l * 512 + wave * 128;
#pragma unroll
            for (int s = 0; s < 4; s++) { binit(acc[s][0], bb + s * 32); binit(acc[s][1], bb + s * 32); }
            gemm_flip<16, 4, 2>(wo, 512, wave * 128, hS, HS, acc);

#pragma unroll
            for (int s = 0; s < 4; s++) {
                // exchange: send acc[s][1-q], receive partner's -> other half of my row
                float exch[16];
#pragma unroll
                for (int i = 0; i < 16; i++) {
                    float snd = q ? acc[s][0][i] : acc[s][1][i];
                    exch[i] = __shfl_xor(snd, 32, 64);
                }
                float A0[16], A1[16];   // half-0 / half-1 param values for row = lane
#pragma unroll
                for (int i = 0; i < 16; i++) {
                    float kept = q ? acc[s][1][i] : acc[s][0][i];
                    A0[i] = q ? exch[i] : kept;
                    A1[i] = q ? kept : exch[i];
                }
                float P[25];
#pragma unroll
                for (int p = 0; p < 25; p++) {
                    int rg = (p & 3) + 4 * (p >> 3);
                    P[p] = ((p >> 2) & 1) ? A1[rg] : A0[rg];
                }
                // ---- spline for (row = lane, unmasked feature u = 4*wave + s) ----
                int n = 2 * (4 * wave + s) + par;
                float xv = xS[lane * XS + n];
                float ew[8], eh[8], sw = 0.f, sh2 = 0.f;
#pragma unroll
                for (int i = 0; i < 8; i++) { ew[i] = __expf(P[i]); sw += ew[i]; }
#pragma unroll
                for (int i = 0; i < 8; i++) { eh[i] = __expf(P[8 + i]); sh2 += eh[i]; }
                float fw = WSCALE * frcp(sw), fh = WSCALE * frcp(sh2);
                float w[8], hh[8];
#pragma unroll
                for (int i = 0; i < 8; i++) { w[i] = fmaf(ew[i], fw, MIN_BIN); hh[i] = fmaf(eh[i], fh, MIN_BIN); }

                bool inside = (xv > -10.0f) && (xv < 10.0f);
                float xc = fminf(fmaxf(xv, -10.0f), 10.0f);
                float cx = -10.0f + w[0], cy = -10.0f + hh[0];
                float xk = -10.0f, yk = -10.0f, bw = w[0], bh = hh[0];
                float udk = P[16], udk1 = P[17];
#pragma unroll
                for (int i = 1; i < 8; i++) {
                    bool take = (xc >= cx);
                    if (take) { xk = cx; yk = cy; bw = w[i]; bh = hh[i]; udk = P[16 + i]; udk1 = P[17 + i]; }
                    cx += w[i]; cy += hh[i];
                }
                float dk  = __logf(1.f + __expf(udk  + SOFTPLUS_OFF)) + MIN_SLOPE;
                float dk1 = __logf(1.f + __expf(udk1 + SOFTPLUS_OFF)) + MIN_SLOPE;
                float ibw = frcp(bw);
                float s_ = bh * ibw;
                float z = fminf(fmaxf((xc - xk) * ibw, 0.0f), 1.0f);
                float omz = 1.0f - z;
                float zz = z * omz;
                float denom = fmaf(dk1 + dk - 2.0f * s_, zz, s_);
                float idenom = frcp(denom);
                float y = fmaf(bh * fmaf(s_ * z, z, dk * zz), idenom, yk);
                float num = fmaf(dk1 * z, z, fmaf(2.0f * s_, zz, dk * omz * omz));
                float ldv = 2.0f * __logf(s_ * idenom) + __logf(num);
                xS[lane * XS + n] = inside ? y : xv;
                ld_acc += inside ? ldv : 0.0f;
            }
            __syncthreads();
        }
    }
    // ---- epilogue: logp + logdet ----
    {
        int m = tid & 63, jg = tid >> 6;
        float s2 = 0.f;
#pragma unroll
        for (int j = 0; j < 8; j++) { float v = xS[m * XS + jg * 8 + j]; s2 += v * v; }
        redS[tid] = ld_acc - 0.5f * s2;
        __syncthreads();
        if (tid < 64) {
            float tot = redS[tid] + redS[tid + 64] + redS[tid + 128] + redS[tid + 192]
                      + *sld - 29.406033062549525f;   // -0.5*N*log(2*pi)
            out[rowbase + tid] = tot;
        }
    }
}

extern "C" void kernel_launch(void* const* d_in, const int* in_sizes, int n_in,
                              void* d_out, int out_size, void* d_ws, size_t ws_size,
                              hipStream_t stream) {
    if (ws_size < WS_NEEDED) return;   // scratch too small: fail loudly (poisoned out)
    const float* x    = (const float*)d_in[0];
    const float* scS  = (const float*)d_in[1];
    const float* scB  = (const float*)d_in[2];
    const float* Win  = (const float*)d_in[3];
    const float* bin  = (const float*)d_in[4];
    const float* W1a  = (const float*)d_in[5];
    const float* b1a  = (const float*)d_in[6];
    const float* W1b  = (const float*)d_in[7];
    const float* b1b  = (const float*)d_in[8];
    const float* W2a  = (const float*)d_in[9];
    const float* b2a  = (const float*)d_in[10];
    const float* W2b  = (const float*)d_in[11];
    const float* b2b  = (const float*)d_in[12];
    const float* Wout = (const float*)d_in[13];
    const float* bout = (const float*)d_in[14];
    const int* perms  = (const int*)d_in[15];

    short* wt   = (short*)d_ws;
    float* bo_t = (float*)((char*)d_ws + WT_BYTES);
    float* sld  = bo_t + NLAYER * 512;

    prep_kernel<<<657, 256, 0, stream>>>(Win, W1a, W1b, W2a, W2b, Wout, bout, scS, wt, bo_t, sld);
    flow_kernel<<<65536 / 64, 256, 0, stream>>>(x, scS, scB, bin, b1a, b1b, b2a, b2b,
                                                perms, wt, bo_t, sld, (float*)d_out);
}